// Round 8
// baseline (285.357 us; speedup 1.0000x reference)
//
#include <hip/hip_runtime.h>
#include <hip/hip_bf16.h>
#include <math.h>

#define IN_DIM 256
#define HID 64
#define OUT_DIM 40
#define EPS_RES 0.3f
#define SCAN_BLK 256

typedef __attribute__((ext_vector_type(8))) short short8v;   // bf16x8 frag (4 VGPR)
typedef __attribute__((ext_vector_type(4))) float f32x4;     // MFMA C/D frag

__device__ __forceinline__ float tanh_fast(float u) {
    float t = __expf(2.0f * u);
    return 1.0f - 2.0f / (t + 1.0f);
}

__device__ __forceinline__ short f2bf(float f) {
    __hip_bfloat16 b = __float2bfloat16(f);
    return __builtin_bit_cast(short, b);
}

// ---------------------------------------------------------------- degree
__global__ void k_deg(const int* __restrict__ dst, int* __restrict__ deg, int E) {
    int i = blockIdx.x * blockDim.x + threadIdx.x;
    if (i < E) atomicAdd(&deg[dst[i]], 1);
}

__global__ void k_dinv(const int* __restrict__ deg, float* __restrict__ dinv, int N) {
    int i = blockIdx.x * blockDim.x + threadIdx.x;
    if (i < N) dinv[i] = rsqrtf(fmaxf((float)deg[i], 1.0f));
}

// ------------------------------------------------------- CSR build: scan
__global__ void k_scan_block(const int* __restrict__ deg, int* __restrict__ incl,
                             int* __restrict__ bsum, int N) {
    __shared__ int sm[SCAN_BLK];
    int tid = threadIdx.x;
    int i = blockIdx.x * SCAN_BLK + tid;
    sm[tid] = (i < N) ? deg[i] : 0;
    __syncthreads();
    for (int off = 1; off < SCAN_BLK; off <<= 1) {
        int t = (tid >= off) ? sm[tid - off] : 0;
        __syncthreads();
        sm[tid] += t;
        __syncthreads();
    }
    if (i < N) incl[i] = sm[tid];
    if (tid == SCAN_BLK - 1) bsum[blockIdx.x] = sm[tid];
}

// NB <= 256
__global__ void k_scan_tops(const int* __restrict__ bsum, int* __restrict__ boff, int NB) {
    __shared__ int sm[SCAN_BLK];
    int tid = threadIdx.x;
    int v = (tid < NB) ? bsum[tid] : 0;
    sm[tid] = v;
    __syncthreads();
    for (int off = 1; off < SCAN_BLK; off <<= 1) {
        int t = (tid >= off) ? sm[tid - off] : 0;
        __syncthreads();
        sm[tid] += t;
        __syncthreads();
    }
    if (tid < NB) boff[tid] = sm[tid] - v;  // exclusive block offsets
}

__global__ void k_scan_add(const int* __restrict__ incl, const int* __restrict__ boff,
                           const int* __restrict__ deg, int* __restrict__ rowp,
                           int* __restrict__ cursor, int N) {
    int i = blockIdx.x * SCAN_BLK + threadIdx.x;
    if (i >= N) return;
    int inc = incl[i] + boff[blockIdx.x];
    rowp[i + 1] = inc;
    cursor[i] = inc - deg[i];
    if (i == 0) rowp[0] = 0;
}

__global__ void k_place(const int* __restrict__ src, const int* __restrict__ dst,
                        int* __restrict__ cursor, int* __restrict__ ssrc, int E) {
    int i = blockIdx.x * blockDim.x + threadIdx.x;
    if (i >= E) return;
    int t = dst[i];
    int p = atomicAdd(&cursor[t], 1);
    ssrc[p] = src[i];
}

// ------------------------------------------------ W1 f32 -> bf16 (one-time)
__global__ void k_wconv(const float* __restrict__ w, short* __restrict__ wpre, int n) {
    int i = blockIdx.x * blockDim.x + threadIdx.x;
    if (i < n) wpre[i] = f2bf(w[i]);
}

// --------------------- x0 = relu(h @ W1^T + b1) via MFMA bf16, fused gate proj
// Block = 4 waves; wave wv owns rows [blk*64+wv*16, +16). Per K-step (K=32):
//   A-frag straight from global h: lane -> row=(l&15), k=(l>>4)*8 (+0..7):
//   two dwordx4 = 16 full 128B lines per instr (zero waste), cvt f32->bf16.
//   B-frags (4 n-tiles) from pre-converted bf16 W1 (L2-resident, 16B/lane).
// C/D layout (m89): col = lane&15, row = (lane>>4)*4 + reg.
__global__ __launch_bounds__(256) void k_gemm1(
    const float* __restrict__ h, const short* __restrict__ wpre,
    const float* __restrict__ b, const float* __restrict__ gw,
    float* __restrict__ out, float* __restrict__ gpa, float* __restrict__ gpb,
    int N) {
    int tid = threadIdx.x;
    int lane = tid & 63;
    int l15 = lane & 15, lhi = lane >> 4;
    int wv = __builtin_amdgcn_readfirstlane(tid >> 6);
    int base = blockIdx.x * 64 + wv * 16;          // wave's row-tile base

    int ra = base + l15;                           // A-load row (per lane)
    if (ra >= N) ra = N - 1;
    const float* arow = h + (size_t)ra * IN_DIM + lhi * 8;

    f32x4 acc[4] = {{0.f,0.f,0.f,0.f},{0.f,0.f,0.f,0.f},
                    {0.f,0.f,0.f,0.f},{0.f,0.f,0.f,0.f}};

#pragma unroll
    for (int ks = 0; ks < 8; ++ks) {
        const float4* ap = (const float4*)(arow + ks * 32);
        float4 a0 = ap[0], a1 = ap[1];
        short8v af;
        af[0] = f2bf(a0.x); af[1] = f2bf(a0.y);
        af[2] = f2bf(a0.z); af[3] = f2bf(a0.w);
        af[4] = f2bf(a1.x); af[5] = f2bf(a1.y);
        af[6] = f2bf(a1.z); af[7] = f2bf(a1.w);

        const short* wk = wpre + (size_t)l15 * IN_DIM + ks * 32 + lhi * 8;
#pragma unroll
        for (int t = 0; t < 4; ++t) {
            short8v bf = *(const short8v*)(wk + t * 16 * IN_DIM);
            acc[t] = __builtin_amdgcn_mfma_f32_16x16x32_bf16(af, bf, acc[t], 0, 0, 0);
        }
    }

    // ---- epilogue: bias+relu, stores, gate partials (D: col=l15, row=lhi*4+r)
#pragma unroll
    for (int r = 0; r < 4; ++r) {
        int grow = base + lhi * 4 + r;
        float vals[4];
        float pa = 0.f, pb = 0.f;
#pragma unroll
        for (int t = 0; t < 4; ++t) {
            int col = t * 16 + l15;
            float v = fmaxf(acc[t][r] + b[col], 0.f);
            vals[t] = v;
            pa = fmaf(v, gw[col], pa);
            pb = fmaf(v, gw[HID + col], pb);
        }
        if (grow < N) {
            float* o = out + (size_t)grow * HID;
#pragma unroll
            for (int t = 0; t < 4; ++t) o[t * 16 + l15] = vals[t];
        }
#pragma unroll
        for (int m = 1; m < 16; m <<= 1) {
            pa += __shfl_xor(pa, m);
            pb += __shfl_xor(pb, m);
        }
        if (l15 == 0 && grow < N) {
            gpa[grow] = pa;
            gpb[grow] = pb;
        }
    }
}

// ---- gather: z[t] = EPS*raw[t] + sum_e tanh(ga[t]+gb[s]+bias)*d[t]*d[s]*x[s]
// one wave per node, lane = hid dim. Edge coefficients computed in a PARALLEL
// phase (lane i -> edge k+i: one tanh per edge, not per lane), then a
// broadcast phase feeds (s_j, e_j) via v_readlane (uniform j -> SGPR) into
// the 64-wide x-row FMA, 2-unrolled for two loads in flight.
__global__ __launch_bounds__(256) void k_gather(
    const int* __restrict__ rowp, const int* __restrict__ ssrc,
    const float* __restrict__ gpa, const float* __restrict__ gpb,
    const float* __restrict__ dinv, const float* __restrict__ gbias,
    const float* __restrict__ x, const float* __restrict__ raw,
    float* __restrict__ z,
    const float* __restrict__ gw_next, float* __restrict__ gpa_next,
    float* __restrict__ gpb_next, int N) {
    int lane = threadIdx.x & 63;
    int wv = __builtin_amdgcn_readfirstlane(threadIdx.x >> 6);
    int t = blockIdx.x * 4 + wv;
    if (t >= N) return;

    float at = gpa[t] + gbias[0];
    float dt = dinv[t];
    float acc = EPS_RES * raw[((size_t)t << 6) + lane];
    int k0 = rowp[t];
    int end = rowp[t + 1];

    for (int kc = k0; kc < end; kc += 64) {
        int cnt = end - kc;
        if (cnt > 64) cnt = 64;
        // parallel phase: lane i computes edge kc+i's coefficient
        int idx = kc + ((lane < cnt) ? lane : 0);
        int sv = ssrc[idx];
        float ev = tanh_fast(at + gpb[sv]) * dt * dinv[sv];
        int evi = __builtin_bit_cast(int, ev);
        // broadcast phase
        int j = 0;
        for (; j + 2 <= cnt; j += 2) {
            int s0 = __builtin_amdgcn_readlane(sv, j);
            int s1 = __builtin_amdgcn_readlane(sv, j + 1);
            float e0 = __builtin_bit_cast(float, __builtin_amdgcn_readlane(evi, j));
            float e1 = __builtin_bit_cast(float, __builtin_amdgcn_readlane(evi, j + 1));
            float x0 = x[((size_t)s0 << 6) + lane];
            float x1 = x[((size_t)s1 << 6) + lane];
            acc = fmaf(e0, x0, acc);
            acc = fmaf(e1, x1, acc);
        }
        if (j < cnt) {
            int s0 = __builtin_amdgcn_readlane(sv, j);
            float e0 = __builtin_bit_cast(float, __builtin_amdgcn_readlane(evi, j));
            acc = fmaf(e0, x[((size_t)s0 << 6) + lane], acc);
        }
    }
    z[((size_t)t << 6) + lane] = acc;

    if (gw_next) {
        float pa = acc * gw_next[lane];
        float pb = acc * gw_next[HID + lane];
#pragma unroll
        for (int m = 32; m; m >>= 1) {
            pa += __shfl_xor(pa, m);
            pb += __shfl_xor(pb, m);
        }
        if (lane == 0) {
            gpa_next[t] = pa;
            gpb_next[t] = pb;
        }
    }
}

// ------------------------------------- logits = x @ W2^T + b2, log_softmax
// 4 rows per wave (16 lanes/row); lane owns cols {l15, l15+16, l15+32(<40)}.
// Block covers 16 rows -> grid = ceil(N/16) (round-7 bug: was ceil(N/256)).
__global__ __launch_bounds__(256) void k_head(
    const float* __restrict__ x, const float* __restrict__ w2,
    const float* __restrict__ b2, float* __restrict__ out, int N) {
    int lane = threadIdx.x & 63;
    int wv = threadIdx.x >> 6;
    int l15 = lane & 15;
    int g = lane >> 4;                         // row-group within wave
    int nrow = blockIdx.x * 16 + wv * 4 + g;
    bool valid = nrow < N;
    int n = valid ? nrow : (N - 1);
    bool has2 = (l15 < 8);                     // col l15+32 exists (<40)

    const float4* xr = (const float4*)(x + (size_t)n * HID);
    const float* w0 = w2 + (size_t)l15 * HID;
    const float* w1 = w0 + 16 * HID;
    const float* wq = w2 + (size_t)(has2 ? (l15 + 32) : l15) * HID;

    float a0 = b2[l15];
    float a1 = b2[l15 + 16];
    float a2 = has2 ? b2[l15 + 32] : 0.f;

#pragma unroll
    for (int kb = 0; kb < HID / 4; ++kb) {
        float4 xv = xr[kb];
        const float* p0 = w0 + kb * 4;
        const float* p1 = w1 + kb * 4;
        const float* p2 = wq + kb * 4;
        a0 = fmaf(xv.x, p0[0], a0); a0 = fmaf(xv.y, p0[1], a0);
        a0 = fmaf(xv.z, p0[2], a0); a0 = fmaf(xv.w, p0[3], a0);
        a1 = fmaf(xv.x, p1[0], a1); a1 = fmaf(xv.y, p1[1], a1);
        a1 = fmaf(xv.z, p1[2], a1); a1 = fmaf(xv.w, p1[3], a1);
        a2 = fmaf(xv.x, p2[0], a2); a2 = fmaf(xv.y, p2[1], a2);
        a2 = fmaf(xv.z, p2[2], a2); a2 = fmaf(xv.w, p2[3], a2);
    }

    float a2m = has2 ? a2 : -1e30f;
    float m = fmaxf(fmaxf(a0, a1), a2m);
#pragma unroll
    for (int mm = 1; mm < 16; mm <<= 1) m = fmaxf(m, __shfl_xor(m, mm));
    float s = expf(a0 - m) + expf(a1 - m) + (has2 ? expf(a2 - m) : 0.f);
#pragma unroll
    for (int mm = 1; mm < 16; mm <<= 1) s += __shfl_xor(s, mm);
    float lse = m + logf(s);

    if (valid) {
        float* o = out + (size_t)nrow * OUT_DIM;
        o[l15] = a0 - lse;
        o[l15 + 16] = a1 - lse;
        if (has2) o[l15 + 32] = a2 - lse;
    }
}

// ----------------------------------------------------------------- launcher
extern "C" void kernel_launch(void* const* d_in, const int* in_sizes, int n_in,
                              void* d_out, int out_size, void* d_ws, size_t ws_size,
                              hipStream_t stream) {
    const float* h    = (const float*)d_in[0];
    const int*   src  = (const int*)d_in[1];
    const int*   dst  = (const int*)d_in[2];
    const float* t1_w = (const float*)d_in[3];
    const float* t1_b = (const float*)d_in[4];
    const float* gw1  = (const float*)d_in[5];
    const float* gb1  = (const float*)d_in[6];
    const float* gw2  = (const float*)d_in[7];
    const float* gb2  = (const float*)d_in[8];
    const float* t2_w = (const float*)d_in[9];
    const float* t2_b = (const float*)d_in[10];
    float* out = (float*)d_out;

    const int N = in_sizes[0] / IN_DIM;
    const int E = in_sizes[1];
    const int NB = (N + SCAN_BLK - 1) / SCAN_BLK;

    // workspace layout
    float* ws   = (float*)d_ws;
    float* raw  = ws;                          // N*64
    float* xA   = raw + (size_t)N * HID;       // N*64
    float* xB   = xA + (size_t)N * HID;        // N*64
    float* dinv = xB + (size_t)N * HID;        // N
    float* gpa1 = dinv + N;                    // N
    float* gpb1 = gpa1 + N;                    // N
    float* gpa2 = gpb1 + N;                    // N
    float* gpb2 = gpa2 + N;                    // N
    short* wpre = (short*)(gpb2 + N);          // HID*IN_DIM bf16 (32KB)
    int* deg    = (int*)(wpre + HID * IN_DIM); // N
    int* incl   = deg + N;                     // N
    int* rowp   = incl + N;                    // N+1
    int* cursor = rowp + N + 1;                // N
    int* bsum   = cursor + N;                  // NB
    int* boff   = bsum + NB;                   // NB
    int* ssrc   = boff + NB;                   // E

    const int TB = 256;
    hipMemsetAsync(deg, 0, (size_t)N * sizeof(int), stream);
    k_deg<<<(E + TB - 1) / TB, TB, 0, stream>>>(dst, deg, E);
    k_dinv<<<NB, TB, 0, stream>>>(deg, dinv, N);
    k_scan_block<<<NB, TB, 0, stream>>>(deg, incl, bsum, N);
    k_scan_tops<<<1, TB, 0, stream>>>(bsum, boff, NB);
    k_scan_add<<<NB, TB, 0, stream>>>(incl, boff, deg, rowp, cursor, N);
    k_place<<<(E + TB - 1) / TB, TB, 0, stream>>>(src, dst, cursor, ssrc, E);

    k_wconv<<<(HID * IN_DIM + TB - 1) / TB, TB, 0, stream>>>(t1_w, wpre, HID * IN_DIM);

    // x0 = relu(h W1^T + b1), plus layer-1 gate projections
    k_gemm1<<<(N + 63) / 64, TB, 0, stream>>>(h, wpre, t1_b, gw1, raw, gpa1, gpb1, N);

    // layer 1: raw -> xA (epilogue computes layer-2 gate projections)
    k_gather<<<(N + 3) / 4, TB, 0, stream>>>(rowp, ssrc, gpa1, gpb1, dinv, gb1,
                                             raw, raw, xA, gw2, gpa2, gpb2, N);

    // layer 2: xA -> xB
    k_gather<<<(N + 3) / 4, TB, 0, stream>>>(rowp, ssrc, gpa2, gpb2, dinv, gb2,
                                             xA, raw, xB, nullptr, nullptr, nullptr, N);

    // 16 rows per block (4 waves x 4 rows)
    k_head<<<(N + 15) / 16, TB, 0, stream>>>(xB, t2_w, t2_b, out, N);
}

// Round 9
// 219.826 us; speedup vs baseline: 1.2981x; 1.2981x over previous
//
#include <hip/hip_runtime.h>
#include <hip/hip_bf16.h>
#include <math.h>

#define IN_DIM 256
#define HID 64
#define OUT_DIM 40
#define EPS_RES 0.3f
#define SCAN_BLK 256

typedef __attribute__((ext_vector_type(8))) short short8v;   // bf16x8 frag (4 VGPR)
typedef __attribute__((ext_vector_type(4))) float f32x4;     // MFMA C/D frag

__device__ __forceinline__ float tanh_fast(float u) {
    float t = __expf(2.0f * u);
    return 1.0f - 2.0f / (t + 1.0f);
}

__device__ __forceinline__ short f2bf(float f) {
    __hip_bfloat16 b = __float2bfloat16(f);
    return __builtin_bit_cast(short, b);
}

// ---------------------------------------------------------------- degree
__global__ void k_deg(const int* __restrict__ dst, int* __restrict__ deg, int E) {
    int i = blockIdx.x * blockDim.x + threadIdx.x;
    if (i < E) atomicAdd(&deg[dst[i]], 1);
}

__global__ void k_dinv(const int* __restrict__ deg, float* __restrict__ dinv, int N) {
    int i = blockIdx.x * blockDim.x + threadIdx.x;
    if (i < N) dinv[i] = rsqrtf(fmaxf((float)deg[i], 1.0f));
}

// ------------------------------------------------------- CSR build: scan
__global__ void k_scan_block(const int* __restrict__ deg, int* __restrict__ incl,
                             int* __restrict__ bsum, int N) {
    __shared__ int sm[SCAN_BLK];
    int tid = threadIdx.x;
    int i = blockIdx.x * SCAN_BLK + tid;
    sm[tid] = (i < N) ? deg[i] : 0;
    __syncthreads();
    for (int off = 1; off < SCAN_BLK; off <<= 1) {
        int t = (tid >= off) ? sm[tid - off] : 0;
        __syncthreads();
        sm[tid] += t;
        __syncthreads();
    }
    if (i < N) incl[i] = sm[tid];
    if (tid == SCAN_BLK - 1) bsum[blockIdx.x] = sm[tid];
}

// NB <= 256
__global__ void k_scan_tops(const int* __restrict__ bsum, int* __restrict__ boff, int NB) {
    __shared__ int sm[SCAN_BLK];
    int tid = threadIdx.x;
    int v = (tid < NB) ? bsum[tid] : 0;
    sm[tid] = v;
    __syncthreads();
    for (int off = 1; off < SCAN_BLK; off <<= 1) {
        int t = (tid >= off) ? sm[tid - off] : 0;
        __syncthreads();
        sm[tid] += t;
        __syncthreads();
    }
    if (tid < NB) boff[tid] = sm[tid] - v;  // exclusive block offsets
}

__global__ void k_scan_add(const int* __restrict__ incl, const int* __restrict__ boff,
                           const int* __restrict__ deg, int* __restrict__ rowp,
                           int* __restrict__ cursor, int N) {
    int i = blockIdx.x * SCAN_BLK + threadIdx.x;
    if (i >= N) return;
    int inc = incl[i] + boff[blockIdx.x];
    rowp[i + 1] = inc;
    cursor[i] = inc - deg[i];
    if (i == 0) rowp[0] = 0;
}

__global__ void k_place(const int* __restrict__ src, const int* __restrict__ dst,
                        int* __restrict__ cursor, int* __restrict__ ssrc, int E) {
    int i = blockIdx.x * blockDim.x + threadIdx.x;
    if (i >= E) return;
    int t = dst[i];
    int p = atomicAdd(&cursor[t], 1);
    ssrc[p] = src[i];
}

// ------------------------------------------------ W1 f32 -> bf16 (one-time)
__global__ void k_wconv(const float* __restrict__ w, short* __restrict__ wpre, int n) {
    int i = blockIdx.x * blockDim.x + threadIdx.x;
    if (i < n) wpre[i] = f2bf(w[i]);
}

// ------------------------------- W2 f32 -> bf16, padded to 48 rows (one-time)
__global__ void k_w2conv(const float* __restrict__ w2, short* __restrict__ w2p) {
    int i = blockIdx.x * blockDim.x + threadIdx.x;
    if (i >= 48 * HID) return;
    int row = i >> 6;
    w2p[i] = f2bf(row < OUT_DIM ? w2[i] : 0.f);
}

// --------------------- x0 = relu(h @ W1^T + b1) via MFMA bf16, fused gate proj
// Block = 4 waves; wave wv owns rows [blk*64+wv*16, +16). Per K-step (K=32):
//   A-frag straight from global h: lane -> row=(l&15), k=(l>>4)*8 (+0..7):
//   two dwordx4 = 16 full 128B lines per instr (zero waste), cvt f32->bf16.
//   B-frags (4 n-tiles) from pre-converted bf16 W1 (L2-resident, 16B/lane).
// C/D layout (m89): col = lane&15, row = (lane>>4)*4 + reg.
__global__ __launch_bounds__(256) void k_gemm1(
    const float* __restrict__ h, const short* __restrict__ wpre,
    const float* __restrict__ b, const float* __restrict__ gw,
    float* __restrict__ out, float* __restrict__ gpa, float* __restrict__ gpb,
    int N) {
    int tid = threadIdx.x;
    int lane = tid & 63;
    int l15 = lane & 15, lhi = lane >> 4;
    int wv = __builtin_amdgcn_readfirstlane(tid >> 6);
    int base = blockIdx.x * 64 + wv * 16;          // wave's row-tile base

    int ra = base + l15;                           // A-load row (per lane)
    if (ra >= N) ra = N - 1;
    const float* arow = h + (size_t)ra * IN_DIM + lhi * 8;

    f32x4 acc[4] = {{0.f,0.f,0.f,0.f},{0.f,0.f,0.f,0.f},
                    {0.f,0.f,0.f,0.f},{0.f,0.f,0.f,0.f}};

#pragma unroll
    for (int ks = 0; ks < 8; ++ks) {
        const float4* ap = (const float4*)(arow + ks * 32);
        float4 a0 = ap[0], a1 = ap[1];
        short8v af;
        af[0] = f2bf(a0.x); af[1] = f2bf(a0.y);
        af[2] = f2bf(a0.z); af[3] = f2bf(a0.w);
        af[4] = f2bf(a1.x); af[5] = f2bf(a1.y);
        af[6] = f2bf(a1.z); af[7] = f2bf(a1.w);

        const short* wk = wpre + (size_t)l15 * IN_DIM + ks * 32 + lhi * 8;
#pragma unroll
        for (int t = 0; t < 4; ++t) {
            short8v bf = *(const short8v*)(wk + t * 16 * IN_DIM);
            acc[t] = __builtin_amdgcn_mfma_f32_16x16x32_bf16(af, bf, acc[t], 0, 0, 0);
        }
    }

    // ---- epilogue: bias+relu, stores, gate partials (D: col=l15, row=lhi*4+r)
#pragma unroll
    for (int r = 0; r < 4; ++r) {
        int grow = base + lhi * 4 + r;
        float vals[4];
        float pa = 0.f, pb = 0.f;
#pragma unroll
        for (int t = 0; t < 4; ++t) {
            int col = t * 16 + l15;
            float v = fmaxf(acc[t][r] + b[col], 0.f);
            vals[t] = v;
            pa = fmaf(v, gw[col], pa);
            pb = fmaf(v, gw[HID + col], pb);
        }
        if (grow < N) {
            float* o = out + (size_t)grow * HID;
#pragma unroll
            for (int t = 0; t < 4; ++t) o[t * 16 + l15] = vals[t];
        }
#pragma unroll
        for (int m = 1; m < 16; m <<= 1) {
            pa += __shfl_xor(pa, m);
            pb += __shfl_xor(pb, m);
        }
        if (l15 == 0 && grow < N) {
            gpa[grow] = pa;
            gpb[grow] = pb;
        }
    }
}

// ---- gather: z[t] = EPS*raw[t] + sum_e tanh(ga[t]+gb[s]+bias)*d[t]*d[s]*x[s]
// one wave per node, lane = hid dim. Edge coefficients computed in a PARALLEL
// phase (lane i -> edge k+i: one tanh per edge, not per lane), then a
// broadcast phase feeds (s_j, e_j) via v_readlane (uniform j -> SGPR) into
// the 64-wide x-row FMA, 2-unrolled for two loads in flight.
__global__ __launch_bounds__(256) void k_gather(
    const int* __restrict__ rowp, const int* __restrict__ ssrc,
    const float* __restrict__ gpa, const float* __restrict__ gpb,
    const float* __restrict__ dinv, const float* __restrict__ gbias,
    const float* __restrict__ x, const float* __restrict__ raw,
    float* __restrict__ z,
    const float* __restrict__ gw_next, float* __restrict__ gpa_next,
    float* __restrict__ gpb_next, int N) {
    int lane = threadIdx.x & 63;
    int wv = __builtin_amdgcn_readfirstlane(threadIdx.x >> 6);
    int t = blockIdx.x * 4 + wv;
    if (t >= N) return;

    float at = gpa[t] + gbias[0];
    float dt = dinv[t];
    float acc = EPS_RES * raw[((size_t)t << 6) + lane];
    int k0 = rowp[t];
    int end = rowp[t + 1];

    for (int kc = k0; kc < end; kc += 64) {
        int cnt = end - kc;
        if (cnt > 64) cnt = 64;
        // parallel phase: lane i computes edge kc+i's coefficient
        int idx = kc + ((lane < cnt) ? lane : 0);
        int sv = ssrc[idx];
        float ev = tanh_fast(at + gpb[sv]) * dt * dinv[sv];
        int evi = __builtin_bit_cast(int, ev);
        // broadcast phase
        int j = 0;
        for (; j + 2 <= cnt; j += 2) {
            int s0 = __builtin_amdgcn_readlane(sv, j);
            int s1 = __builtin_amdgcn_readlane(sv, j + 1);
            float e0 = __builtin_bit_cast(float, __builtin_amdgcn_readlane(evi, j));
            float e1 = __builtin_bit_cast(float, __builtin_amdgcn_readlane(evi, j + 1));
            float x0 = x[((size_t)s0 << 6) + lane];
            float x1 = x[((size_t)s1 << 6) + lane];
            acc = fmaf(e0, x0, acc);
            acc = fmaf(e1, x1, acc);
        }
        if (j < cnt) {
            int s0 = __builtin_amdgcn_readlane(sv, j);
            float e0 = __builtin_bit_cast(float, __builtin_amdgcn_readlane(evi, j));
            acc = fmaf(e0, x[((size_t)s0 << 6) + lane], acc);
        }
    }
    z[((size_t)t << 6) + lane] = acc;

    if (gw_next) {
        float pa = acc * gw_next[lane];
        float pb = acc * gw_next[HID + lane];
#pragma unroll
        for (int m = 32; m; m >>= 1) {
            pa += __shfl_xor(pa, m);
            pb += __shfl_xor(pb, m);
        }
        if (lane == 0) {
            gpa_next[t] = pa;
            gpb_next[t] = pb;
        }
    }
}

// ------------- head: logits = x @ W2^T + b2, log_softmax — MFMA (gemm1 pattern)
// Wave owns 16 rows; A-frag = x rows (row=l15, k=lhi*8 + ks*32), streamed with
// full-line dwordx4 (every byte used). 3 B-tiles from bf16 W2 padded [48][64]
// (6KB, L1-hot, per-lane row l15+16t — loaded once, outside the row stream).
// 6 MFMAs/wave. D: col=l15, row=lhi*4+r. Softmax over 40 cols = 16-lane
// shfl reduce (lane holds cols {l15, l15+16, l15+32 if l15<8}).
__global__ __launch_bounds__(256) void k_head(
    const float* __restrict__ x, const short* __restrict__ w2p,
    const float* __restrict__ b2, float* __restrict__ out, int N) {
    int tid = threadIdx.x;
    int lane = tid & 63;
    int l15 = lane & 15, lhi = lane >> 4;
    int wv = __builtin_amdgcn_readfirstlane(tid >> 6);
    int base = blockIdx.x * 64 + wv * 16;

    int ra = base + l15;
    if (ra >= N) ra = N - 1;
    const float* arow = x + (size_t)ra * HID + lhi * 8;

    f32x4 acc[3] = {{0.f,0.f,0.f,0.f},{0.f,0.f,0.f,0.f},{0.f,0.f,0.f,0.f}};

#pragma unroll
    for (int ks = 0; ks < 2; ++ks) {
        const float4* ap = (const float4*)(arow + ks * 32);
        float4 a0 = ap[0], a1 = ap[1];
        short8v af;
        af[0] = f2bf(a0.x); af[1] = f2bf(a0.y);
        af[2] = f2bf(a0.z); af[3] = f2bf(a0.w);
        af[4] = f2bf(a1.x); af[5] = f2bf(a1.y);
        af[6] = f2bf(a1.z); af[7] = f2bf(a1.w);

        const short* wk = w2p + (size_t)l15 * HID + ks * 32 + lhi * 8;
#pragma unroll
        for (int t = 0; t < 3; ++t) {
            short8v bf = *(const short8v*)(wk + t * 16 * HID);
            acc[t] = __builtin_amdgcn_mfma_f32_16x16x32_bf16(af, bf, acc[t], 0, 0, 0);
        }
    }

    bool has2 = (l15 < 8);                     // col l15+32 < 40
    float b0 = b2[l15];
    float b1 = b2[l15 + 16];
    float bq = has2 ? b2[l15 + 32] : 0.f;

#pragma unroll
    for (int r = 0; r < 4; ++r) {
        int grow = base + lhi * 4 + r;
        float v0 = acc[0][r] + b0;
        float v1 = acc[1][r] + b1;
        float v2 = acc[2][r] + bq;
        float m = fmaxf(fmaxf(v0, v1), has2 ? v2 : -1e30f);
#pragma unroll
        for (int mm = 1; mm < 16; mm <<= 1) m = fmaxf(m, __shfl_xor(m, mm));
        float s = expf(v0 - m) + expf(v1 - m) + (has2 ? expf(v2 - m) : 0.f);
#pragma unroll
        for (int mm = 1; mm < 16; mm <<= 1) s += __shfl_xor(s, mm);
        float lse = m + logf(s);
        if (grow < N) {
            float* o = out + (size_t)grow * OUT_DIM;
            o[l15] = v0 - lse;
            o[l15 + 16] = v1 - lse;
            if (has2) o[l15 + 32] = v2 - lse;
        }
    }
}

// ----------------------------------------------------------------- launcher
extern "C" void kernel_launch(void* const* d_in, const int* in_sizes, int n_in,
                              void* d_out, int out_size, void* d_ws, size_t ws_size,
                              hipStream_t stream) {
    const float* h    = (const float*)d_in[0];
    const int*   src  = (const int*)d_in[1];
    const int*   dst  = (const int*)d_in[2];
    const float* t1_w = (const float*)d_in[3];
    const float* t1_b = (const float*)d_in[4];
    const float* gw1  = (const float*)d_in[5];
    const float* gb1  = (const float*)d_in[6];
    const float* gw2  = (const float*)d_in[7];
    const float* gb2  = (const float*)d_in[8];
    const float* t2_w = (const float*)d_in[9];
    const float* t2_b = (const float*)d_in[10];
    float* out = (float*)d_out;

    const int N = in_sizes[0] / IN_DIM;
    const int E = in_sizes[1];
    const int NB = (N + SCAN_BLK - 1) / SCAN_BLK;

    // workspace layout
    float* ws   = (float*)d_ws;
    float* raw  = ws;                          // N*64
    float* xA   = raw + (size_t)N * HID;       // N*64
    float* xB   = xA + (size_t)N * HID;        // N*64
    float* dinv = xB + (size_t)N * HID;        // N
    float* gpa1 = dinv + N;                    // N
    float* gpb1 = gpa1 + N;                    // N
    float* gpa2 = gpb1 + N;                    // N
    float* gpb2 = gpa2 + N;                    // N
    short* wpre = (short*)(gpb2 + N);          // HID*IN_DIM bf16 (32KB)
    short* w2p  = wpre + HID * IN_DIM;         // 48*HID bf16 (6KB)
    int* deg    = (int*)(w2p + 48 * HID);      // N
    int* incl   = deg + N;                     // N
    int* rowp   = incl + N;                    // N+1
    int* cursor = rowp + N + 1;                // N
    int* bsum   = cursor + N;                  // NB
    int* boff   = bsum + NB;                   // NB
    int* ssrc   = boff + NB;                   // E

    const int TB = 256;
    hipMemsetAsync(deg, 0, (size_t)N * sizeof(int), stream);
    k_deg<<<(E + TB - 1) / TB, TB, 0, stream>>>(dst, deg, E);
    k_dinv<<<NB, TB, 0, stream>>>(deg, dinv, N);
    k_scan_block<<<NB, TB, 0, stream>>>(deg, incl, bsum, N);
    k_scan_tops<<<1, TB, 0, stream>>>(bsum, boff, NB);
    k_scan_add<<<NB, TB, 0, stream>>>(incl, boff, deg, rowp, cursor, N);
    k_place<<<(E + TB - 1) / TB, TB, 0, stream>>>(src, dst, cursor, ssrc, E);

    k_wconv<<<(HID * IN_DIM + TB - 1) / TB, TB, 0, stream>>>(t1_w, wpre, HID * IN_DIM);
    k_w2conv<<<(48 * HID + TB - 1) / TB, TB, 0, stream>>>(t2_w, w2p);

    // x0 = relu(h W1^T + b1), plus layer-1 gate projections
    k_gemm1<<<(N + 63) / 64, TB, 0, stream>>>(h, wpre, t1_b, gw1, raw, gpa1, gpb1, N);

    // layer 1: raw -> xA (epilogue computes layer-2 gate projections)
    k_gather<<<(N + 3) / 4, TB, 0, stream>>>(rowp, ssrc, gpa1, gpb1, dinv, gb1,
                                             raw, raw, xA, gw2, gpa2, gpb2, N);

    // layer 2: xA -> xB
    k_gather<<<(N + 3) / 4, TB, 0, stream>>>(rowp, ssrc, gpa2, gpb2, dinv, gb2,
                                             xA, raw, xB, nullptr, nullptr, nullptr, N);

    // 64 rows per block (4 waves x 16 rows, MFMA)
    k_head<<<(N + 63) / 64, TB, 0, stream>>>(xB, w2p, t2_b, out, N);
}